// Round 2
// baseline (120.896 us; speedup 1.0000x reference)
//
#include <hip/hip_runtime.h>

// XTermFrequency: per-row histogram + normalize.
//   assignments: [B=512, S=8192] int32 in [0, V=50257)
//   out:         [B, V] float32 = counts / S
//
// R1: parallelize over (row, chunk). One block = one 6400-bin vocab chunk of
// one row (25.6 KB LDS -> 6 blocks/CU resident). Grid 512x8 = 4096 blocks.
// Each block re-reads its row (8x read amplification) but grid is indexed
// (x=row, y=chunk) so a row's 8 blocks share linear-id mod 8 => same XCD =>
// row re-reads hit that XCD's L2. Output written exactly once, float4-
// vectorized with head/tail alignment fixup (V odd => rotating alignment).

#define TF_BLOCK 256
#define TF_CHUNK 6400    // bins per block (25.6 KB LDS)
#define TF_NCHUNK 8      // 8 * 6400 = 51200 >= 50257
#define TF_I4PT 8        // int4 per thread = S / (4 * TF_BLOCK), S = 8192

__global__ __launch_bounds__(TF_BLOCK)
void XTermFrequency_hist_kernel(const int* __restrict__ assign,
                                float* __restrict__ out,
                                int V, int S, float scale) {
    __shared__ unsigned int hist[TF_CHUNK];
    const int row = blockIdx.x;
    const int base = blockIdx.y * TF_CHUNK;
    const int len = min(V - base, TF_CHUNK);
    const int tid = threadIdx.x;

    // Zero LDS histogram (LDS pipe) while the row loads are in flight (VMEM).
    for (int i = tid; i < TF_CHUNK; i += TF_BLOCK) hist[i] = 0u;

    const int4* rowp = (const int4*)(assign + (size_t)row * S);
    int4 v[TF_I4PT];
#pragma unroll
    for (int k = 0; k < TF_I4PT; ++k) v[k] = rowp[tid + k * TF_BLOCK];

    __syncthreads();

    // Scatter in-range values into the LDS chunk (~12.7% hit rate per chunk).
#pragma unroll
    for (int k = 0; k < TF_I4PT; ++k) {
        unsigned int d;
        d = (unsigned int)(v[k].x - base);
        if (d < (unsigned int)TF_CHUNK) atomicAdd(&hist[d], 1u);
        d = (unsigned int)(v[k].y - base);
        if (d < (unsigned int)TF_CHUNK) atomicAdd(&hist[d], 1u);
        d = (unsigned int)(v[k].z - base);
        if (d < (unsigned int)TF_CHUNK) atomicAdd(&hist[d], 1u);
        d = (unsigned int)(v[k].w - base);
        if (d < (unsigned int)TF_CHUNK) atomicAdd(&hist[d], 1u);
    }
    __syncthreads();

    // Coalesced, float4-vectorized write-out of normalized counts.
    float* dst = out + (size_t)row * V + base;
    int head = (int)((4u - (((unsigned int)(size_t)dst >> 2) & 3u)) & 3u);
    if (head > len) head = len;
    if (tid < head) dst[tid] = (float)hist[tid] * scale;

    const int n4 = (len - head) >> 2;
    float4* __restrict__ dst4 = (float4*)(dst + head);
    for (int j = tid; j < n4; j += TF_BLOCK) {
        const int i = head + 4 * j;
        float4 o;
        o.x = (float)hist[i]     * scale;
        o.y = (float)hist[i + 1] * scale;
        o.z = (float)hist[i + 2] * scale;
        o.w = (float)hist[i + 3] * scale;
        dst4[j] = o;
    }

    const int done = head + 4 * n4;
    const int rem = len - done;
    if (tid < rem) dst[done + tid] = (float)hist[done + tid] * scale;
}

extern "C" void kernel_launch(void* const* d_in, const int* in_sizes, int n_in,
                              void* d_out, int out_size, void* d_ws, size_t ws_size,
                              hipStream_t stream) {
    const int* assign = (const int*)d_in[0];
    float* out = (float*)d_out;

    const int V = 50257;
    const int B = out_size / V;          // 512
    const int S = in_sizes[0] / B;       // 8192
    const float scale = 1.0f / (float)S; // exact power of two

    XTermFrequency_hist_kernel<<<dim3(B, TF_NCHUNK), dim3(TF_BLOCK), 0, stream>>>(
        assign, out, V, S, scale);
}

// Round 3
// 118.784 us; speedup vs baseline: 1.0178x; 1.0178x over previous
//
#include <hip/hip_runtime.h>

// XTermFrequency: per-row histogram + normalize.
//   assignments: [B=512, S=8192] int32 in [0, V=50257)
//   out:         [B, V] float32 = counts / S
//
// R3: one 1024-thread block per row (grid 512 = exactly 2 blocks/CU at
// __launch_bounds__(1024,8) -> 32 waves/CU). Vocab in 3 chunks of 17408 bins
// (68 KB LDS; 2 blocks * 68 = 136 <= 160 KB/CU). Row is RE-LOADED from
// global each chunk (2 int4/thread) instead of held in VGPRs: keeps VGPR
// under the 64-reg/8-wave cap, and re-reads hit L2 (per-XCD row set = 64
// rows * 32 KB = 2 MB <= 4 MB). Read amp to HBM ~1x, write exactly once.
// scale = 1/8192 is a power of two -> outputs exact.

#define TF_BLOCK 1024
#define TF_CHUNK 17408          // 17 * 1024 bins = 68 KB LDS
#define TF_NCHUNK 3             // 3 * 17408 = 52224 >= 50257

__global__ __launch_bounds__(TF_BLOCK, 8)
void XTermFrequency_hist_kernel(const int* __restrict__ assign,
                                float* __restrict__ out,
                                int V, int S, float scale) {
    __shared__ unsigned int hist[TF_CHUNK];
    const int row = blockIdx.x;
    const int tid = threadIdx.x;

    const int4* __restrict__ rowp = (const int4*)(assign + (size_t)row * S);
    const int n4row = S >> 2;                    // 2048 int4 per row
    float* const orow = out + (size_t)row * V;

    for (int c = 0; c < TF_NCHUNK; ++c) {
        const int base = c * TF_CHUNK;
        const int len = min(V - base, TF_CHUNK);

        // Zero this chunk's histogram (17 exact strides).
#pragma unroll
        for (int i = 0; i < TF_CHUNK / TF_BLOCK; ++i)
            hist[tid + i * TF_BLOCK] = 0u;
        __syncthreads();

        // Scan the row (re-load; L2-resident after chunk 0), scatter in-range.
        for (int idx = tid; idx < n4row; idx += TF_BLOCK) {
            const int4 v = rowp[idx];
            unsigned int d;
            d = (unsigned int)(v.x - base);
            if (d < (unsigned int)TF_CHUNK) atomicAdd(&hist[d], 1u);
            d = (unsigned int)(v.y - base);
            if (d < (unsigned int)TF_CHUNK) atomicAdd(&hist[d], 1u);
            d = (unsigned int)(v.z - base);
            if (d < (unsigned int)TF_CHUNK) atomicAdd(&hist[d], 1u);
            d = (unsigned int)(v.w - base);
            if (d < (unsigned int)TF_CHUNK) atomicAdd(&hist[d], 1u);
        }
        __syncthreads();

        // Coalesced float4 write-out (head/tail fixup: V odd => rotating align).
        float* dst = orow + base;
        int head = (int)((4u - (((unsigned int)(size_t)dst >> 2) & 3u)) & 3u);
        if (head > len) head = len;
        if (tid < head) dst[tid] = (float)hist[tid] * scale;

        const int n4 = (len - head) >> 2;
        float4* __restrict__ dst4 = (float4*)(dst + head);
        for (int j = tid; j < n4; j += TF_BLOCK) {
            const int i = head + 4 * j;
            float4 o;
            o.x = (float)hist[i]     * scale;
            o.y = (float)hist[i + 1] * scale;
            o.z = (float)hist[i + 2] * scale;
            o.w = (float)hist[i + 3] * scale;
            dst4[j] = o;
        }

        const int done = head + 4 * n4;
        const int rem = len - done;
        if (tid < rem) dst[done + tid] = (float)hist[done + tid] * scale;

        __syncthreads();  // protect hist from next chunk's zeroing
    }
}

extern "C" void kernel_launch(void* const* d_in, const int* in_sizes, int n_in,
                              void* d_out, int out_size, void* d_ws, size_t ws_size,
                              hipStream_t stream) {
    const int* assign = (const int*)d_in[0];
    float* out = (float*)d_out;

    const int V = 50257;
    const int B = out_size / V;          // 512
    const int S = in_sizes[0] / B;       // 8192
    const float scale = 1.0f / (float)S; // exact power of two

    XTermFrequency_hist_kernel<<<dim3(B), dim3(TF_BLOCK), 0, stream>>>(
        assign, out, V, S, scale);
}